// Round 1
// baseline (725.799 us; speedup 1.0000x reference)
//
#include <hip/hip_runtime.h>
#include <math.h>

// Problem constants: B=1, C=64, D=H=W=16, HEADS=4, HD=16
#define NPOS 4096          // D*H*W
#define CN   262144        // C * NPOS = 64*4096 floats per [C, D, H, W] tensor

// ---------------------------------------------------------------------------
// Stage 1: spatial conv 3x3 over (H,W), per depth slice. pad (0,1,1).
// y1[co, d, h, w] = b[co] + sum_{ci,dh,dw} w[co,ci,0,dh,dw] * x[ci,d,h+dh-1,w+dw-1]
// grid: 64*16 blocks (co,d), 256 threads = one (h,w) per thread.
__global__ void conv_sp_kernel(const float* __restrict__ x, const float* __restrict__ w,
                               const float* __restrict__ b, float* __restrict__ y) {
    __shared__ float ws[576];
    int co = blockIdx.x >> 4;
    int d  = blockIdx.x & 15;
    int tid = threadIdx.x;
    for (int idx = tid; idx < 576; idx += 256) ws[idx] = w[co * 576 + idx];
    __syncthreads();
    int h = tid >> 4, wq = tid & 15;
    float acc = b[co];
    const float* xs = x + d * 256;
    for (int ci = 0; ci < 64; ++ci) {
        const float* xc = xs + ci * 4096;
        const float* wc = ws + ci * 9;
        #pragma unroll
        for (int dh = 0; dh < 3; ++dh) {
            int hh = h + dh - 1;
            if (hh < 0 || hh > 15) continue;
            #pragma unroll
            for (int dw = 0; dw < 3; ++dw) {
                int ww = wq + dw - 1;
                if (ww < 0 || ww > 15) continue;
                acc += wc[dh * 3 + dw] * xc[hh * 16 + ww];
            }
        }
    }
    y[co * 4096 + d * 256 + tid] = acc;
}

// ---------------------------------------------------------------------------
// Stage 2: spectral conv, 3 taps over D. pad (1,0,0).
// y2[co,d,h,w] = b[co] + sum_{ci,t} w[co,ci,t] * y1[ci, d+t-1, h, w]
__global__ void conv_spec_kernel(const float* __restrict__ y1, const float* __restrict__ w,
                                 const float* __restrict__ b, float* __restrict__ y2) {
    __shared__ float ws[192];
    int co = blockIdx.x >> 4;
    int d  = blockIdx.x & 15;
    int tid = threadIdx.x;
    if (tid < 192) ws[tid] = w[co * 192 + tid];
    __syncthreads();
    float acc = b[co];
    int p = d * 256 + tid;
    for (int ci = 0; ci < 64; ++ci) {
        const float* yc = y1 + ci * 4096 + p;
        if (d > 0)  acc += ws[ci * 3 + 0] * yc[-256];
        acc += ws[ci * 3 + 1] * yc[0];
        if (d < 15) acc += ws[ci * 3 + 2] * yc[256];
    }
    y2[co * 4096 + p] = acc;
}

// ---------------------------------------------------------------------------
// Stage 3: 1x1x1 QKV conv, writing TRANSPOSED per-head layouts [head][pos][dim]
// so attention can load a key/value vector with 4x float4.
// q is pre-scaled by 1/sqrt(HD) = 0.25.
__global__ void qkv_kernel(const float* __restrict__ y2, const float* __restrict__ w,
                           const float* __restrict__ b,
                           float* __restrict__ qt, float* __restrict__ kt,
                           float* __restrict__ vt) {
    __shared__ float ws[64];
    int oc = blockIdx.x >> 4;   // 0..191
    int d  = blockIdx.x & 15;
    int tid = threadIdx.x;
    if (tid < 64) ws[tid] = w[oc * 64 + tid];
    __syncthreads();
    float acc = b[oc];
    int p = d * 256 + tid;
    for (int ci = 0; ci < 64; ++ci) acc += ws[ci] * y2[ci * 4096 + p];
    int which = oc >> 6;        // 0=q 1=k 2=v
    int hd = oc & 63;
    int head = hd >> 4, dim = hd & 15;
    if (which == 0) acc *= 0.25f;   // fold 1/sqrt(HD) into q
    float* dst = (which == 0) ? qt : ((which == 1) ? kt : vt);
    dst[head * 65536 + p * 16 + dim] = acc;
}

// ---------------------------------------------------------------------------
// Stage 4: retention attention. One wave per query (head, i, j, kq).
// z[m,n,o] = (q . k_{m,n,o}) * g^(|i-m|+|j-kq|) * g^(|n-o|)   (q pre-scaled)
// softmax over o (16-lane segments), out[d] = sum_{m,n,o} p * v[d,m,n,o].
__global__ __launch_bounds__(256) void attn_kernel(
        const float* __restrict__ qt, const float* __restrict__ kt,
        const float* __restrict__ vt, const float* __restrict__ gamma,
        float* __restrict__ ao) {
    __shared__ float gp[48];
    int tid = threadIdx.x;
    if (tid < 48) {
        float g = 1.f / (1.f + __expf(-gamma[0]));
        gp[tid] = exp2f((float)tid * log2f(g));
    }
    __syncthreads();
    int lane = tid & 63;
    int qidx = blockIdx.x * 4 + (tid >> 6);   // 0..16383
    int head = qidx >> 12;
    int p = qidx & 4095;
    int i = p >> 8, j = (p >> 4) & 15, kq = p & 15;

    const float4* q4 = (const float4*)(qt + head * 65536 + p * 16);
    float4 qa = q4[0], qb = q4[1], qc = q4[2], qd = q4[3];

    float acc[16];
    #pragma unroll
    for (int d2 = 0; d2 < 16; ++d2) acc[d2] = 0.f;

    int ejk = abs(j - kq);
    for (int m = 0; m < 16; ++m) {
        float cdec = gp[abs(i - m) + ejk];
        const float* kb = kt + head * 65536 + m * 4096;  // 256 keys * 16 dims
        const float* vb = vt + head * 65536 + m * 4096;
        #pragma unroll
        for (int t = 0; t < 4; ++t) {
            int ki = t * 64 + lane;          // local key: n = ki>>4, o = ki&15
            const float4* kk = (const float4*)(kb + ki * 16);
            float4 k0 = kk[0], k1 = kk[1], k2 = kk[2], k3 = kk[3];
            float dot = qa.x*k0.x + qa.y*k0.y + qa.z*k0.z + qa.w*k0.w
                      + qb.x*k1.x + qb.y*k1.y + qb.z*k1.z + qb.w*k1.w
                      + qc.x*k2.x + qc.y*k2.y + qc.z*k2.z + qc.w*k2.w
                      + qd.x*k3.x + qd.y*k3.y + qd.z*k3.z + qd.w*k3.w;
            int n = ki >> 4, o = ki & 15;
            float z = dot * cdec * gp[abs(n - o)];
            // softmax over o: 16-lane segments (lanes with same n)
            float mx = z;
            #pragma unroll
            for (int s = 1; s < 16; s <<= 1) mx = fmaxf(mx, __shfl_xor(mx, s));
            float e = __expf(z - mx);
            float sm = e;
            #pragma unroll
            for (int s = 1; s < 16; s <<= 1) sm += __shfl_xor(sm, s);
            float pr = e / sm;
            const float4* vv = (const float4*)(vb + ki * 16);
            float4 v0 = vv[0], v1 = vv[1], v2 = vv[2], v3 = vv[3];
            acc[0]  += pr * v0.x; acc[1]  += pr * v0.y;
            acc[2]  += pr * v0.z; acc[3]  += pr * v0.w;
            acc[4]  += pr * v1.x; acc[5]  += pr * v1.y;
            acc[6]  += pr * v1.z; acc[7]  += pr * v1.w;
            acc[8]  += pr * v2.x; acc[9]  += pr * v2.y;
            acc[10] += pr * v2.z; acc[11] += pr * v2.w;
            acc[12] += pr * v3.x; acc[13] += pr * v3.y;
            acc[14] += pr * v3.z; acc[15] += pr * v3.w;
        }
    }
    // full 64-lane reduction of the 16 accumulators
    #pragma unroll
    for (int s = 1; s < 64; s <<= 1) {
        #pragma unroll
        for (int d2 = 0; d2 < 16; ++d2) acc[d2] += __shfl_xor(acc[d2], s);
    }
    if (lane == 0) {
        #pragma unroll
        for (int d2 = 0; d2 < 16; ++d2)
            ao[(head * 16 + d2) * 4096 + p] = acc[d2];
    }
}

// ---------------------------------------------------------------------------
// Stage 5: 1x1x1 projection conv.
__global__ void proj_kernel(const float* __restrict__ ao, const float* __restrict__ w,
                            const float* __restrict__ b, float* __restrict__ out) {
    __shared__ float ws[64];
    int oc = blockIdx.x >> 4;
    int d  = blockIdx.x & 15;
    int tid = threadIdx.x;
    if (tid < 64) ws[tid] = w[oc * 64 + tid];
    __syncthreads();
    float acc = b[oc];
    int p = d * 256 + tid;
    for (int ci = 0; ci < 64; ++ci) acc += ws[ci] * ao[ci * 4096 + p];
    out[oc * 4096 + p] = acc;
}

// ---------------------------------------------------------------------------
extern "C" void kernel_launch(void* const* d_in, const int* in_sizes, int n_in,
                              void* d_out, int out_size, void* d_ws, size_t ws_size,
                              hipStream_t stream) {
    const float* x      = (const float*)d_in[0];
    const float* gamma  = (const float*)d_in[1];
    const float* w_sp   = (const float*)d_in[2];
    const float* b_sp   = (const float*)d_in[3];
    const float* w_spec = (const float*)d_in[4];
    const float* b_spec = (const float*)d_in[5];
    const float* w_qkv  = (const float*)d_in[6];
    const float* b_qkv  = (const float*)d_in[7];
    const float* w_proj = (const float*)d_in[8];
    const float* b_proj = (const float*)d_in[9];
    float* out = (float*)d_out;

    float* ws = (float*)d_ws;
    float* y1 = ws;            // [64][4096]
    float* y2 = ws + CN;       // [64][4096]
    float* qt = ws + 2 * CN;   // [4][4096][16]
    float* kt = ws + 3 * CN;   // [4][4096][16]
    float* vt = ws + 4 * CN;   // [4][4096][16]
    float* ao = ws + 5 * CN;   // [64][4096]

    conv_sp_kernel  <<<1024, 256, 0, stream>>>(x, w_sp, b_sp, y1);
    conv_spec_kernel<<<1024, 256, 0, stream>>>(y1, w_spec, b_spec, y2);
    qkv_kernel      <<<3072, 256, 0, stream>>>(y2, w_qkv, b_qkv, qt, kt, vt);
    attn_kernel     <<<4096, 256, 0, stream>>>(qt, kt, vt, gamma, ao);
    proj_kernel     <<<1024, 256, 0, stream>>>(ao, w_proj, b_proj, out);
}

// Round 2
// 383.481 us; speedup vs baseline: 1.8927x; 1.8927x over previous
//
#include <hip/hip_runtime.h>
#include <math.h>

// Problem constants: B=1, C=64, D=H=W=16, HEADS=4, HD=16
#define CN   262144        // C * 4096 floats per [C, D, H, W] tensor

// ---------------------------------------------------------------------------
// Stage 1: spatial conv 3x3 over (H,W), per depth slice. pad (0,1,1).
// Block per (co-group-of-4, d); thread = (wave=co, h, w-quad); float4 outputs.
__global__ __launch_bounds__(256) void conv_sp_kernel(
        const float* __restrict__ x, const float* __restrict__ w,
        const float* __restrict__ b, float* __restrict__ y) {
    __shared__ float ws[2304];          // 4 co x 576
    int cog = blockIdx.x >> 4;          // 0..15
    int d   = blockIdx.x & 15;
    int tid = threadIdx.x;
    for (int idx = tid; idx < 2304; idx += 256) ws[idx] = w[cog * 4 * 576 + idx];
    __syncthreads();
    int wv = tid >> 6;                  // wave -> co within group
    int co = cog * 4 + wv;
    int t  = tid & 63;
    int h  = t >> 2;
    int wq = t & 3;                     // w base = wq*4
    float bias = b[co];
    float ax = bias, ay = bias, az = bias, aw = bias;
    const float* wsc = ws + wv * 576;
    for (int ci = 0; ci < 64; ++ci) {
        const float* row = x + ci * 4096 + d * 256;
        const float* wc  = wsc + ci * 9;
        #pragma unroll
        for (int dh = 0; dh < 3; ++dh) {
            int hh = h + dh - 1;
            if (hh < 0 || hh > 15) continue;
            const float* r = row + hh * 16 + wq * 4;
            float4 q0 = *(const float4*)r;
            float lm = (wq > 0) ? r[-1] : 0.f;
            float rp = (wq < 3) ? r[4]  : 0.f;
            float wL = wc[dh * 3 + 0], wM = wc[dh * 3 + 1], wR = wc[dh * 3 + 2];
            ax += wL * lm   + wM * q0.x + wR * q0.y;
            ay += wL * q0.x + wM * q0.y + wR * q0.z;
            az += wL * q0.y + wM * q0.z + wR * q0.w;
            aw += wL * q0.z + wM * q0.w + wR * rp;
        }
    }
    float4 out = {ax, ay, az, aw};
    *(float4*)(y + co * 4096 + d * 256 + t * 4) = out;
}

// ---------------------------------------------------------------------------
// Stage 2: spectral conv, 3 taps over D. pad (1,0,0). float4 over positions.
__global__ __launch_bounds__(256) void conv_spec_kernel(
        const float* __restrict__ y1, const float* __restrict__ w,
        const float* __restrict__ b, float* __restrict__ y2) {
    __shared__ float ws[192];
    int co = blockIdx.x >> 2;
    int pb = blockIdx.x & 3;
    int tid = threadIdx.x;
    if (tid < 192) ws[tid] = w[co * 192 + tid];
    __syncthreads();
    int p0 = (pb * 256 + tid) * 4;      // float index, 4 consecutive positions
    int d  = p0 >> 8;
    float bias = b[co];
    float ax = bias, ay = bias, az = bias, aw = bias;
    for (int ci = 0; ci < 64; ++ci) {
        const float* base = y1 + ci * 4096 + p0;
        float w0 = ws[ci * 3], w1 = ws[ci * 3 + 1], w2 = ws[ci * 3 + 2];
        if (d > 0) {
            float4 a = *(const float4*)(base - 256);
            ax += w0 * a.x; ay += w0 * a.y; az += w0 * a.z; aw += w0 * a.w;
        }
        float4 m = *(const float4*)base;
        ax += w1 * m.x; ay += w1 * m.y; az += w1 * m.z; aw += w1 * m.w;
        if (d < 15) {
            float4 c = *(const float4*)(base + 256);
            ax += w2 * c.x; ay += w2 * c.y; az += w2 * c.z; aw += w2 * c.w;
        }
    }
    float4 out = {ax, ay, az, aw};
    *(float4*)(y2 + co * 4096 + p0) = out;
}

// ---------------------------------------------------------------------------
// Stage 3: 1x1x1 QKV conv -> transposed [head][pos][dim]; q pre-scaled 0.25.
__global__ __launch_bounds__(256) void qkv_kernel(
        const float* __restrict__ y2, const float* __restrict__ w,
        const float* __restrict__ b,
        float* __restrict__ qt, float* __restrict__ kt, float* __restrict__ vt) {
    __shared__ float ws[64];
    int oc = blockIdx.x >> 2;           // 0..191
    int pb = blockIdx.x & 3;
    int tid = threadIdx.x;
    if (tid < 64) ws[tid] = w[oc * 64 + tid];
    __syncthreads();
    int p0 = (pb * 256 + tid) * 4;
    float bias = b[oc];
    float ax = bias, ay = bias, az = bias, aw = bias;
    for (int ci = 0; ci < 64; ++ci) {
        float4 a = *(const float4*)(y2 + ci * 4096 + p0);
        float wc = ws[ci];
        ax += wc * a.x; ay += wc * a.y; az += wc * a.z; aw += wc * a.w;
    }
    int which = oc >> 6;                // 0=q 1=k 2=v
    int hd = oc & 63;
    int head = hd >> 4, dim = hd & 15;
    if (which == 0) { ax *= 0.25f; ay *= 0.25f; az *= 0.25f; aw *= 0.25f; }
    float* dst = (which == 0) ? qt : ((which == 1) ? kt : vt);
    dst += head * 65536 + p0 * 16 + dim;
    dst[0]  = ax; dst[16] = ay; dst[32] = az; dst[48] = aw;
}

// ---------------------------------------------------------------------------
// Stage 4: retention attention, shuffle-free softmax.
// Block = (head, i, j-pair) -> 32 queries. Wave w: j = jp*2+(w>>1),
// kq in (w&1)*8 + {qg*2, qg*2+1}. Lane = (qg=lane>>4, n=lane&15); lane owns
// the full o-row (softmax group) for its n; m-slabs staged in LDS.
__global__ __launch_bounds__(256, 2) void attn_kernel(
        const float* __restrict__ qt, const float* __restrict__ kt,
        const float* __restrict__ vt, const float* __restrict__ gamma,
        float* __restrict__ ao) {
    __shared__ float ksh[4160];         // 16 n x (260) padded rows
    __shared__ float vsh[4160];
    __shared__ float qsh[512];
    __shared__ float gp[32];
    int tid = threadIdx.x;
    int bI = blockIdx.x;
    int head = bI >> 7;
    int i    = (bI >> 3) & 15;
    int jp   = bI & 7;

    if (tid < 32) {
        float g = 1.f / (1.f + __expf(-gamma[0]));
        gp[tid] = __powf(g, (float)tid);
    }
    if (tid < 128) {
        const float4* src = (const float4*)(qt + head * 65536 + (i * 256 + jp * 32) * 16);
        ((float4*)qsh)[tid] = src[tid];
    }
    __syncthreads();

    int wv   = tid >> 6;
    int lane = tid & 63;
    int qg   = lane >> 4;
    int n    = lane & 15;
    int j    = jp * 2 + (wv >> 1);
    int qb0  = wv * 8 + qg * 2;         // local query index (qq=0)
    int kq0  = qb0 & 15;

    float4 qreg[2][4];
    #pragma unroll
    for (int qq = 0; qq < 2; ++qq) {
        const float4* qs = (const float4*)(qsh + (qb0 + qq) * 16);
        #pragma unroll
        for (int r = 0; r < 4; ++r) qreg[qq][r] = qs[r];
    }
    float wdec[16];
    #pragma unroll
    for (int o = 0; o < 16; ++o) wdec[o] = gp[abs(n - o)];
    int ejk0 = abs(j - kq0);
    int ejk1 = abs(j - (kq0 + 1));

    float4 acc[2][4];
    #pragma unroll
    for (int qq = 0; qq < 2; ++qq)
        #pragma unroll
        for (int r = 0; r < 4; ++r) acc[qq][r] = make_float4(0.f, 0.f, 0.f, 0.f);

    const float* kbase = kt + head * 65536;
    const float* vbase = vt + head * 65536;

    for (int m = 0; m < 16; ++m) {
        __syncthreads();                // everyone done reading previous slab
        {
            const float4* ks = (const float4*)(kbase + m * 4096);
            const float4* vs = (const float4*)(vbase + m * 4096);
            #pragma unroll
            for (int u = 0; u < 4; ++u) {
                int c = tid + 256 * u;
                int f = 4 * c;
                int nn = f >> 8;
                int col = f & 255;
                *(float4*)(ksh + nn * 260 + col) = ks[c];
                *(float4*)(vsh + nn * 260 + col) = vs[c];
            }
        }
        __syncthreads();

        float c0 = gp[abs(i - m) + ejk0];
        float c1 = gp[abs(i - m) + ejk1];
        float z[2][16];
        const float* krow = ksh + n * 260;
        #pragma unroll
        for (int o = 0; o < 16; ++o) {
            float4 k0 = *(const float4*)(krow + o * 16);
            float4 k1 = *(const float4*)(krow + o * 16 + 4);
            float4 k2 = *(const float4*)(krow + o * 16 + 8);
            float4 k3 = *(const float4*)(krow + o * 16 + 12);
            #pragma unroll
            for (int qq = 0; qq < 2; ++qq) {
                float4 a0 = qreg[qq][0], a1 = qreg[qq][1];
                float4 a2 = qreg[qq][2], a3 = qreg[qq][3];
                float dot = a0.x * k0.x + a0.y * k0.y + a0.z * k0.z + a0.w * k0.w
                          + a1.x * k1.x + a1.y * k1.y + a1.z * k1.z + a1.w * k1.w
                          + a2.x * k2.x + a2.y * k2.y + a2.z * k2.z + a2.w * k2.w
                          + a3.x * k3.x + a3.y * k3.y + a3.z * k3.z + a3.w * k3.w;
                z[qq][o] = dot * (qq ? c1 : c0) * wdec[o];
            }
        }
        #pragma unroll
        for (int qq = 0; qq < 2; ++qq) {
            float mx = z[qq][0];
            #pragma unroll
            for (int o = 1; o < 16; ++o) mx = fmaxf(mx, z[qq][o]);
            float sm = 0.f;
            #pragma unroll
            for (int o = 0; o < 16; ++o) {
                float e = __expf(z[qq][o] - mx);
                z[qq][o] = e;
                sm += e;
            }
            float inv = __builtin_amdgcn_rcpf(sm);
            #pragma unroll
            for (int o = 0; o < 16; ++o) z[qq][o] *= inv;
        }
        const float* vrow = vsh + n * 260;
        #pragma unroll
        for (int o = 0; o < 16; ++o) {
            float4 v0 = *(const float4*)(vrow + o * 16);
            float4 v1 = *(const float4*)(vrow + o * 16 + 4);
            float4 v2 = *(const float4*)(vrow + o * 16 + 8);
            float4 v3 = *(const float4*)(vrow + o * 16 + 12);
            #pragma unroll
            for (int qq = 0; qq < 2; ++qq) {
                float p = z[qq][o];
                acc[qq][0].x += p * v0.x; acc[qq][0].y += p * v0.y;
                acc[qq][0].z += p * v0.z; acc[qq][0].w += p * v0.w;
                acc[qq][1].x += p * v1.x; acc[qq][1].y += p * v1.y;
                acc[qq][1].z += p * v1.z; acc[qq][1].w += p * v1.w;
                acc[qq][2].x += p * v2.x; acc[qq][2].y += p * v2.y;
                acc[qq][2].z += p * v2.z; acc[qq][2].w += p * v2.w;
                acc[qq][3].x += p * v3.x; acc[qq][3].y += p * v3.y;
                acc[qq][3].z += p * v3.z; acc[qq][3].w += p * v3.w;
            }
        }
    }

    // reduce over the 16 n-lanes (xor butterfly stays within the 16-lane group)
    #pragma unroll
    for (int qq = 0; qq < 2; ++qq) {
        #pragma unroll
        for (int r = 0; r < 4; ++r) {
            #pragma unroll
            for (int s = 1; s < 16; s <<= 1) {
                acc[qq][r].x += __shfl_xor(acc[qq][r].x, s);
                acc[qq][r].y += __shfl_xor(acc[qq][r].y, s);
                acc[qq][r].z += __shfl_xor(acc[qq][r].z, s);
                acc[qq][r].w += __shfl_xor(acc[qq][r].w, s);
            }
        }
    }
    if (n == 0) {
        #pragma unroll
        for (int qq = 0; qq < 2; ++qq) {
            int p = i * 256 + j * 16 + kq0 + qq;
            float* base = ao + head * 16 * 4096 + p;
            #pragma unroll
            for (int r = 0; r < 4; ++r) {
                base[(4 * r + 0) * 4096] = acc[qq][r].x;
                base[(4 * r + 1) * 4096] = acc[qq][r].y;
                base[(4 * r + 2) * 4096] = acc[qq][r].z;
                base[(4 * r + 3) * 4096] = acc[qq][r].w;
            }
        }
    }
}

// ---------------------------------------------------------------------------
// Stage 5: 1x1x1 projection conv, float4 over positions.
__global__ __launch_bounds__(256) void proj_kernel(
        const float* __restrict__ ao, const float* __restrict__ w,
        const float* __restrict__ b, float* __restrict__ out) {
    __shared__ float ws[64];
    int oc = blockIdx.x >> 2;
    int pb = blockIdx.x & 3;
    int tid = threadIdx.x;
    if (tid < 64) ws[tid] = w[oc * 64 + tid];
    __syncthreads();
    int p0 = (pb * 256 + tid) * 4;
    float bias = b[oc];
    float ax = bias, ay = bias, az = bias, aw = bias;
    for (int ci = 0; ci < 64; ++ci) {
        float4 a = *(const float4*)(ao + ci * 4096 + p0);
        float wc = ws[ci];
        ax += wc * a.x; ay += wc * a.y; az += wc * a.z; aw += wc * a.w;
    }
    float4 o4 = {ax, ay, az, aw};
    *(float4*)(out + oc * 4096 + p0) = o4;
}

// ---------------------------------------------------------------------------
extern "C" void kernel_launch(void* const* d_in, const int* in_sizes, int n_in,
                              void* d_out, int out_size, void* d_ws, size_t ws_size,
                              hipStream_t stream) {
    const float* x      = (const float*)d_in[0];
    const float* gamma  = (const float*)d_in[1];
    const float* w_sp   = (const float*)d_in[2];
    const float* b_sp   = (const float*)d_in[3];
    const float* w_spec = (const float*)d_in[4];
    const float* b_spec = (const float*)d_in[5];
    const float* w_qkv  = (const float*)d_in[6];
    const float* b_qkv  = (const float*)d_in[7];
    const float* w_proj = (const float*)d_in[8];
    const float* b_proj = (const float*)d_in[9];
    float* out = (float*)d_out;

    float* ws = (float*)d_ws;
    float* y1 = ws;            // [64][4096]
    float* y2 = ws + CN;       // [64][4096]
    float* qt = ws + 2 * CN;   // [4][4096][16]
    float* kt = ws + 3 * CN;   // [4][4096][16]
    float* vt = ws + 4 * CN;   // [4][4096][16]
    float* ao = ws + 5 * CN;   // [64][4096]

    conv_sp_kernel  <<<256, 256, 0, stream>>>(x, w_sp, b_sp, y1);
    conv_spec_kernel<<<256, 256, 0, stream>>>(y1, w_spec, b_spec, y2);
    qkv_kernel      <<<768, 256, 0, stream>>>(y2, w_qkv, b_qkv, qt, kt, vt);
    attn_kernel     <<<512, 256, 0, stream>>>(qt, kt, vt, gamma, ao);
    proj_kernel     <<<256, 256, 0, stream>>>(ao, w_proj, b_proj, out);
}